// Round 7
// baseline (688.252 us; speedup 1.0000x reference)
//
#include <hip/hip_runtime.h>

typedef unsigned short ushort_t;
typedef __attribute__((ext_vector_type(4))) float f32x4;
typedef __attribute__((ext_vector_type(8))) short s16x8;
typedef __attribute__((ext_vector_type(8))) unsigned short u16x8;

#define NNODE 2592
#define NEDGE 912
#define MATSZ (512*512)
#define NBLOCKS 512

__device__ __forceinline__ ushort_t f2b(float f){
  union {unsigned int i; float f;} x; x.f = f;
  unsigned int r = (x.i + 0x7fffu + ((x.i>>16)&1u))>>16;
  return (ushort_t)r;
}
__device__ __forceinline__ void async_copy16(const ushort_t* g, ushort_t* l){
  __builtin_amdgcn_global_load_lds((const __attribute__((address_space(1))) void*)g,
                                   (__attribute__((address_space(3))) void*)l, 16, 0, 0);
}

// Coherent (agent-scope, L2-bypassing) accessors for inter-phase buffers.
// These hit the memory-side coherent point, so NO cache-invalidating fences
// are needed at phase barriers — L2 stays warm for weights/inputs.
__device__ __forceinline__ float cload(const float* p){
  return __hip_atomic_load(p, __ATOMIC_RELAXED, __HIP_MEMORY_SCOPE_AGENT);
}
__device__ __forceinline__ void cstore(float* p, float v){
  __hip_atomic_store(p, v, __ATOMIC_RELAXED, __HIP_MEMORY_SCOPE_AGENT);
}
__device__ __forceinline__ float2 cload2(const float* p){
  union{unsigned long long u; float2 f;} x;
  x.u = __hip_atomic_load((const unsigned long long*)p, __ATOMIC_RELAXED,
                          __HIP_MEMORY_SCOPE_AGENT);
  return x.f;
}
__device__ __forceinline__ void cstore2(float* p, float2 v){
  union{unsigned long long u; float2 f;} x; x.f = v;
  __hip_atomic_store((unsigned long long*)p, x.u, __ATOMIC_RELAXED,
                     __HIP_MEMORY_SCOPE_AGENT);
}

union SMem {
  struct { ushort_t As[2][64][72]; ushort_t Bs[2][128*64]; } g;  // 18432+32768 B
  float tile[64][65];                                            // 16640 B
};

// Grid barrier, monotonic counter. Arrival is RELEASE (drains this block's
// prior sc-stores). Polls RELAXED. fence=true only for the WT-publication
// barrier (normal cached stores in P0 need wbl2 + inv once).
__device__ __forceinline__ void grid_sync(unsigned int* cnt, unsigned int nb,
                                          unsigned int target, bool fence){
  __syncthreads();
  if (threadIdx.x==0){
    if (fence) __builtin_amdgcn_fence(__ATOMIC_RELEASE, "agent");
    __hip_atomic_fetch_add(cnt, 1u, __ATOMIC_RELEASE, __HIP_MEMORY_SCOPE_AGENT);
    while (__hip_atomic_load(cnt, __ATOMIC_RELAXED,
                             __HIP_MEMORY_SCOPE_AGENT) < nb*target)
      __builtin_amdgcn_s_sleep(16);
    if (fence) __builtin_amdgcn_fence(__ATOMIC_ACQUIRE, "agent");
  }
  __syncthreads();
}

// ---- transpose+convert one 64x64 tile of one weight matrix ----
__device__ void transpose_unit(SMem* sm, unsigned u,
    const float* __restrict__ fc1, const float* __restrict__ hc,
    const float* __restrict__ m0, const float* __restrict__ m1,
    const float* __restrict__ ms, ushort_t* __restrict__ WT)
{
  unsigned w = u>>6, t = u&63;
  const float* src = (w==0) ? fc1
                   : (w<4)  ? hc + (size_t)(w-1)*MATSZ
                   : (w<8)  ? m0 + (size_t)(w-4)*MATSZ
                   : (w<12) ? m1 + (size_t)(w-8)*MATSZ
                            : ms + (size_t)(w-12)*MATSZ;
  ushort_t* dst = WT + (size_t)w*MATSZ;
  int r0 = (int)(t>>3)*64, c0 = (int)(t&7)*64;
  #pragma unroll
  for (int j=0;j<16;j++){
    int idx = j*256 + threadIdx.x;
    int r = idx>>6, c = idx&63;
    sm->tile[r][c] = src[(size_t)(r0+r)*512 + c0 + c];
  }
  __syncthreads();
  #pragma unroll
  for (int j=0;j<16;j++){
    int idx = j*256 + threadIdx.x;
    int r = idx>>6, c = idx&63;
    dst[(size_t)(c0+r)*512 + r0 + c] = f2b(sm->tile[c][r]);
  }
  __syncthreads();
}

// ---- one 64x128 GEMM tile, double-buffered K-loop, 1 barrier/iter ----
// AMODE 0: A = feats (a/v/l + spk_emb);  1: hyperedge combine;  2: fp32 Asrc
template<int AMODE, bool RELU>
__device__ void gemm_unit(SMem* sm, int row0, int col0, int M,
    const float* __restrict__ Asrc, const float* __restrict__ Ebuf,
    const float* __restrict__ he_w,
    const float* __restrict__ inA, const float* __restrict__ inV,
    const float* __restrict__ inL, const float* __restrict__ qmask,
    const float* __restrict__ spk_emb,
    const ushort_t* __restrict__ Wsel, const float* __restrict__ bsel,
    float* __restrict__ Cout, int cst, int cbase)
{
  const int tid = threadIdx.x;
  const int wave = tid>>6, lane = tid&63;
  const int ml = lane&15, quad = lane>>4;
  const int wr = wave>>1, wc = wave&1;
  const int ar = tid>>3, ac8 = (tid&7)*8;

  const float *sr0=nullptr,*sr1=nullptr,*sp0=nullptr,*sp1=nullptr;
  const float *e10=nullptr,*e20=nullptr,*e11=nullptr,*e21=nullptr;
  float c10=0.f,c20=0.f,c11=0.f,c21=0.f;
  const float *g0=nullptr,*g1=nullptr;
  {
    int n0 = row0+ar;     if (n0 > M-1) n0 = M-1;
    int n1 = row0+ar+32;  if (n1 > M-1) n1 = M-1;
    if (AMODE==0){
      int d=n0/162, rm=n0-d*162, m=rm/54, i=rm-m*54, t=d*54+i;
      sr0 = ((m==0)? inL : (m==1)? inA : inV) + (size_t)t*512;
      if (m==0) sp0 = spk_emb + ((qmask[(i*16+d)*2+1]>qmask[(i*16+d)*2])?512:0);
      d=n1/162; rm=n1-d*162; m=rm/54; i=rm-m*54; t=d*54+i;
      sr1 = ((m==0)? inL : (m==1)? inA : inV) + (size_t)t*512;
      if (m==0) sp1 = spk_emb + ((qmask[(i*16+d)*2+1]>qmask[(i*16+d)*2])?512:0);
    } else if (AMODE==1){
      int d=n0/162, rm=n0-d*162, m=rm/54, i=rm-m*54;
      int em=d*57+m, eu=d*57+3+i;
      float w1=he_w[em], w2=he_w[eu], inv=1.0f/(w1+w2+1e-8f);
      c10=w1*inv; c20=w2*inv; e10=Ebuf+(size_t)em*512; e20=Ebuf+(size_t)eu*512;
      d=n1/162; rm=n1-d*162; m=rm/54; i=rm-m*54;
      em=d*57+m; eu=d*57+3+i;
      w1=he_w[em]; w2=he_w[eu]; inv=1.0f/(w1+w2+1e-8f);
      c11=w1*inv; c21=w2*inv; e11=Ebuf+(size_t)em*512; e21=Ebuf+(size_t)eu*512;
    } else {
      g0 = Asrc + (size_t)n0*512;
      g1 = Asrc + (size_t)n1*512;
    }
  }

  f32x4 acc[2][4];
  #pragma unroll
  for (int mi=0;mi<2;mi++)
    #pragma unroll
    for (int j=0;j<4;j++) acc[mi][j] = (f32x4){0.f,0.f,0.f,0.f};

  const int lr = lane>>3;
  const int lchunk = lane&7;
  const int bswz = (lchunk ^ lr)*8;

  float2 ra0[4], ra1[4], rb0[4], rb1[4];   // raw prefetch regs

  auto issueA = [&](int kk){
    if (AMODE==0){
      #pragma unroll
      for (int j=0;j<4;j++){
        ra0[j] = *(const float2*)(sr0+kk+ac8+2*j);
        ra1[j] = *(const float2*)(sr1+kk+ac8+2*j);
      }
      if (sp0){
        #pragma unroll
        for (int j=0;j<4;j++) rb0[j] = *(const float2*)(sp0+kk+ac8+2*j);
      }
      if (sp1){
        #pragma unroll
        for (int j=0;j<4;j++) rb1[j] = *(const float2*)(sp1+kk+ac8+2*j);
      }
    } else if (AMODE==1){
      #pragma unroll
      for (int j=0;j<4;j++){
        ra0[j] = cload2(e10+kk+ac8+2*j);
        rb0[j] = cload2(e20+kk+ac8+2*j);
        ra1[j] = cload2(e11+kk+ac8+2*j);
        rb1[j] = cload2(e21+kk+ac8+2*j);
      }
    } else {
      #pragma unroll
      for (int j=0;j<4;j++){
        ra0[j] = cload2(g0+kk+ac8+2*j);
        ra1[j] = cload2(g1+kk+ac8+2*j);
      }
    }
  };
  auto dmaB = [&](int kk, int b){
    #pragma unroll
    for (int rep=0; rep<4; rep++){
      int bn0 = wave*32 + rep*8;
      const ushort_t* s = Wsel + (size_t)(col0 + bn0 + lr)*512 + kk + bswz;
      async_copy16(s, &sm->g.Bs[b][bn0*64]);
    }
  };

  dmaB(0, 0);
  issueA(0);

  for (int kt=0; kt<8; kt++){
    const int buf = kt & 1;
    u16x8 av0, av1;
    if (AMODE==0){
      #pragma unroll
      for (int j=0;j<4;j++){
        float2 a = ra0[j], b = ra1[j];
        if (sp0){ a.x += rb0[j].x; a.y += rb0[j].y; }
        if (sp1){ b.x += rb1[j].x; b.y += rb1[j].y; }
        av0[2*j]=f2b(a.x); av0[2*j+1]=f2b(a.y);
        av1[2*j]=f2b(b.x); av1[2*j+1]=f2b(b.y);
      }
    } else if (AMODE==1){
      #pragma unroll
      for (int j=0;j<4;j++){
        av0[2*j]   = f2b(c10*ra0[j].x + c20*rb0[j].x);
        av0[2*j+1] = f2b(c10*ra0[j].y + c20*rb0[j].y);
        av1[2*j]   = f2b(c11*ra1[j].x + c21*rb1[j].x);
        av1[2*j+1] = f2b(c11*ra1[j].y + c21*rb1[j].y);
      }
    } else {
      #pragma unroll
      for (int j=0;j<4;j++){
        av0[2*j]=f2b(ra0[j].x); av0[2*j+1]=f2b(ra0[j].y);
        av1[2*j]=f2b(ra1[j].x); av1[2*j+1]=f2b(ra1[j].y);
      }
    }
    *(u16x8*)&sm->g.As[buf][ar][ac8]    = av0;
    *(u16x8*)&sm->g.As[buf][ar+32][ac8] = av1;
    __syncthreads();   // As[buf] visible to all; drains B(kt) DMA residual
    if (kt<7){ dmaB((kt+1)*64, buf^1); issueA((kt+1)*64); }  // hidden under MFMA
    #pragma unroll
    for (int kh=0; kh<2; kh++){
      s16x8 a0 = *(const s16x8*)&sm->g.As[buf][wr*32 + ml][kh*32 + quad*8];
      s16x8 a1 = *(const s16x8*)&sm->g.As[buf][wr*32 + 16 + ml][kh*32 + quad*8];
      s16x8 b[4];
      #pragma unroll
      for (int j=0;j<4;j++){
        int bn = wc*64 + j*16 + ml;
        b[j] = *(const s16x8*)&sm->g.Bs[buf][bn*64 + (((kh*4+quad) ^ (bn&7))<<3)];
      }
      #pragma unroll
      for (int j=0;j<4;j++){
        acc[0][j] = __builtin_amdgcn_mfma_f32_16x16x32_bf16(a0,b[j],acc[0][j],0,0,0);
        acc[1][j] = __builtin_amdgcn_mfma_f32_16x16x32_bf16(a1,b[j],acc[1][j],0,0,0);
      }
    }
  }

  #pragma unroll
  for (int j=0;j<4;j++){
    int wcol = col0 + wc*64 + j*16 + ml;
    float bv = bsel ? bsel[wcol] : 0.f;
    int c = cbase + wcol;
    #pragma unroll
    for (int mi=0;mi<2;mi++){
      int rb = row0 + wr*32 + mi*16 + quad*4;
      f32x4 a = acc[mi][j];
      #pragma unroll
      for (int r=0;r<4;r++){
        int rr = rb + r;
        if (rr < M){
          float v = a[r] + bv;
          if (RELU) v = fmaxf(v, 0.f);
          cstore(Cout + (size_t)rr*cst + c, v);
        }
      }
    }
  }
  __syncthreads();   // protect LDS against next unit's writes
}

// ---- one hyperedge: e = (sum w*x)/(sum w+eps) + attr ----
__device__ void edge_unit(int e, const float* __restrict__ X,
    const float* __restrict__ ew, const int* __restrict__ het,
    const float* __restrict__ at1, const float* __restrict__ at2,
    float* __restrict__ E)
{
  int d = e/57, r = e - d*57;
  int col = threadIdx.x*2;
  float sx=0.f, sy=0.f, de=0.f;
  if (r < 3){
    int nnz0 = d*324 + r*54;
    const float* row = X + ((size_t)(d*162 + r*54))*512 + col;
    #pragma unroll 6
    for (int i=0;i<54;i++){
      float w = ew[nnz0+i];
      float2 x = cload2(row);
      sx += w*x.x; sy += w*x.y; de += w;
      row += 512;
    }
  } else {
    int i = r-3;
    int nnz0 = d*324 + 162 + i*3;
    #pragma unroll
    for (int m=0;m<3;m++){
      float w = ew[nnz0+m];
      float2 x = cload2(X + ((size_t)(d*162 + m*54 + i))*512 + col);
      sx += w*x.x; sy += w*x.y; de += w;
    }
  }
  float invde = 1.0f/(de + 1e-8f);
  const float* at = het[e] ? at1 : at2;
  float2 o;
  o.x = sx*invde + at[col];
  o.y = sy*invde + at[col+1];
  cstore2(E + (size_t)e*512 + col, o);
}

// ---- per-(group,speaker) column sums of X ----
__device__ void gsum_unit(unsigned char* spks, int u, const float* __restrict__ X,
    const float* __restrict__ qmask, float* __restrict__ Gsum)
{
  int g = u>>1, d = g/3;
  int col = (u&1)*256 + threadIdx.x;
  if (threadIdx.x < 54)
    spks[threadIdx.x] = qmask[(threadIdx.x*16+d)*2+1] > qmask[(threadIdx.x*16+d)*2];
  __syncthreads();
  size_t base = (size_t)g*54*512 + col;
  float s0=0.f, s1=0.f;
  #pragma unroll 6
  for (int i=0;i<54;i++){
    float x = cload(X + base + (size_t)i*512);
    if (spks[i]) s1 += x; else s0 += x;
  }
  cstore(Gsum + (size_t)(g*2)*512 + col, s0);
  cstore(Gsum + (size_t)(g*2+1)*512 + col, s1);
  __syncthreads();
}

// ---- fused RGCN combine + next-layer Gsum (+final output & denoise) ----
template<bool LAST>
__device__ void sf_unit(unsigned char* spks, float* red, int u,
    const float* __restrict__ Gin, const float* __restrict__ H1,
    const float* __restrict__ HS, const float* __restrict__ Sp,
    const float* __restrict__ qmask, float* __restrict__ Gout,
    float* __restrict__ Gsum, const float* __restrict__ OUThg,
    float* __restrict__ dout, float* __restrict__ acc,
    unsigned int* __restrict__ done)
{
  int g = u>>1, d = g/3;
  int col = (u&1)*256 + threadIdx.x;
  if (threadIdx.x < 54)
    spks[threadIdx.x] = qmask[(threadIdx.x*16+d)*2+1] > qmask[(threadIdx.x*16+d)*2];
  __syncthreads();
  float S1_0 = cload(Sp + (size_t)(g*2)*1024 + 512 + col);
  float S1_1 = cload(Sp + (size_t)(g*2+1)*1024 + 512 + col);
  float S0_0 = cload(Sp + (size_t)(g*2+1)*1024 + col);
  float S0_1 = cload(Sp + (size_t)(g*2)*1024 + col);
  const float inv = 1.0f/(53.0f + 1e-8f);
  size_t base = (size_t)g*54*512 + col;
  float gs0=0.f, gs1=0.f, sumsq=0.f;
  #pragma unroll 6
  for (int i=0;i<54;i++){
    size_t off = base + (size_t)i*512;
    int sp = spks[i];
    float S1 = sp ? S1_1 : S1_0;
    float S0 = sp ? S0_1 : S0_0;
    float h1 = cload(H1+off), hs = cload(HS+off), gi = cload(Gin+off);
    float f = fmaxf((S1 - h1 + S0)*inv + hs, 0.f);
    float gn = gi + f;
    cstore(Gout+off, gn);
    if (sp) gs1 += gn; else gs0 += gn;
    if (LAST){
      sumsq += f*f;
      dout[off] = cload(OUThg+off) + gn;
    }
  }
  cstore(Gsum + (size_t)(g*2)*512 + col, gs0);
  cstore(Gsum + (size_t)(g*2+1)*512 + col, gs1);
  if (LAST){
    red[threadIdx.x] = sumsq;
    __syncthreads();
    #pragma unroll
    for (int s=128; s>0; s>>=1){
      if (threadIdx.x < s) red[threadIdx.x] += red[threadIdx.x+s];
      __syncthreads();
    }
    if (threadIdx.x == 0){
      atomicAdd(acc, red[0]);
      __threadfence();
      unsigned int old = atomicAdd(done, 1u);
      if (old == 95u){
        float tot = atomicAdd(acc, 0.0f);
        dout[(size_t)NNODE*512] = tot * (1.0f/1327104.0f);
      }
    }
  }
  __syncthreads();
}

// ---------------------------------------------------------------------------
__global__ __launch_bounds__(256,2) void mega_kernel(
    const float* __restrict__ A_in, const float* __restrict__ V_in,
    const float* __restrict__ L_in, const float* __restrict__ qmask,
    const float* __restrict__ spk_emb,
    const float* __restrict__ fc1W, const float* __restrict__ fc1b,
    const float* __restrict__ he_w, const float* __restrict__ ew_w,
    const float* __restrict__ at1, const float* __restrict__ at2,
    const float* __restrict__ hcW, const float* __restrict__ hcb,
    const float* __restrict__ m0W, const float* __restrict__ m1W,
    const float* __restrict__ msW, const float* __restrict__ m3b,
    const int* __restrict__ het,
    ushort_t* __restrict__ WT, float* __restrict__ X1, float* __restrict__ OUT,
    float* __restrict__ H1, float* __restrict__ HS, float* __restrict__ G,
    float* __restrict__ EB, float* __restrict__ Gsum, float* __restrict__ Sp,
    unsigned int* __restrict__ ctrl, float* __restrict__ dout)
{
  __shared__ SMem sm;
  __shared__ unsigned char spks[64];
  __shared__ float red[256];
  unsigned int* cnt  = ctrl;
  unsigned int* done = ctrl + 2;
  float* acc = (float*)(ctrl + 3);
  const unsigned int bid = blockIdx.x, nb = gridDim.x;
  unsigned int tgt = 0;

  // P0: weight transpose (1024 units)
  for (unsigned u=bid; u<1024; u+=nb)
    transpose_unit(&sm, u, fc1W, hcW, m0W, m1W, msW, WT);
  grid_sync(cnt,nb,++tgt,true);   // ONLY fenced barrier: publishes WT

  // P1: X1 = feats @ fc1 + b (164 units)
  for (unsigned u=bid; u<164; u+=nb)
    gemm_unit<0,false>(&sm, (u%41)*64, (u/41)*128, NNODE,
        nullptr,nullptr,nullptr, A_in,V_in,L_in,qmask,spk_emb,
        WT, fc1b, X1, 512, 0);
  grid_sync(cnt,nb,++tgt,false);

  // P2: edge0(912) + gsum(96) + H1_k0(164) + HS_k0(164)
  for (unsigned u=bid; u<1336; u+=nb){
    if (u<912) edge_unit(u, X1, ew_w, het, at1, at2, EB);
    else if (u<1008) gsum_unit(spks, u-912, X1, qmask, Gsum);
    else if (u<1172){ unsigned v=u-1008;
      gemm_unit<2,false>(&sm, (v%41)*64, (v/41)*128, NNODE,
          X1,nullptr,nullptr,nullptr,nullptr,nullptr,nullptr,nullptr,
          WT+(size_t)8*MATSZ, nullptr, H1, 512, 0); }
    else { unsigned v=u-1172;
      gemm_unit<2,false>(&sm, (v%41)*64, (v/41)*128, NNODE,
          X1,nullptr,nullptr,nullptr,nullptr,nullptr,nullptr,nullptr,
          WT+(size_t)12*MATSZ, m3b, HS, 512, 0); }
  }
  grid_sync(cnt,nb,++tgt,false);

  // P3: hgGEMM0(164) + Sp_k0(16)
  for (unsigned u=bid; u<180; u+=nb){
    if (u<164)
      gemm_unit<1,true>(&sm, (u%41)*64, (u/41)*128, NNODE,
          nullptr, EB, he_w, nullptr,nullptr,nullptr,nullptr,nullptr,
          WT+(size_t)1*MATSZ, hcb, OUT, 512, 0);
    else { unsigned v=u-164; int wh=v&1, ct=(v>>1)&3, rt=v>>3;
      gemm_unit<2,false>(&sm, rt*64, ct*128, 96,
          Gsum,nullptr,nullptr,nullptr,nullptr,nullptr,nullptr,nullptr,
          WT+(size_t)(4+wh*4+0)*MATSZ, nullptr, Sp, 1024, wh*512); }
  }
  grid_sync(cnt,nb,++tgt,false);

  // P4: edge1(912, X=OUT) + sf_k0(96)
  for (unsigned u=bid; u<1008; u+=nb){
    if (u<912) edge_unit(u, OUT, ew_w, het, at1, at2, EB);
    else sf_unit<false>(spks, red, u-912, X1, H1, HS, Sp, qmask, G, Gsum,
                        nullptr, nullptr, nullptr, nullptr);
  }
  grid_sync(cnt,nb,++tgt,false);

  // P5: hgGEMM1(164) + H1_k1(164) + HS_k1(164) + Sp_k1(16)
  for (unsigned u=bid; u<508; u+=nb){
    if (u<164)
      gemm_unit<1,true>(&sm, (u%41)*64, (u/41)*128, NNODE,
          nullptr, EB, he_w, nullptr,nullptr,nullptr,nullptr,nullptr,
          WT+(size_t)2*MATSZ, hcb+512, OUT, 512, 0);
    else if (u<328){ unsigned v=u-164;
      gemm_unit<2,false>(&sm, (v%41)*64, (v/41)*128, NNODE,
          G,nullptr,nullptr,nullptr,nullptr,nullptr,nullptr,nullptr,
          WT+(size_t)9*MATSZ, nullptr, H1, 512, 0); }
    else if (u<492){ unsigned v=u-328;
      gemm_unit<2,false>(&sm, (v%41)*64, (v/41)*128, NNODE,
          G,nullptr,nullptr,nullptr,nullptr,nullptr,nullptr,nullptr,
          WT+(size_t)13*MATSZ, m3b+512, HS, 512, 0); }
    else { unsigned v=u-492; int wh=v&1, ct=(v>>1)&3, rt=v>>3;
      gemm_unit<2,false>(&sm, rt*64, ct*128, 96,
          Gsum,nullptr,nullptr,nullptr,nullptr,nullptr,nullptr,nullptr,
          WT+(size_t)(4+wh*4+1)*MATSZ, nullptr, Sp, 1024, wh*512); }
  }
  grid_sync(cnt,nb,++tgt,false);

  // P6: edge2(912, X=OUT) + sf_k1(96)
  for (unsigned u=bid; u<1008; u+=nb){
    if (u<912) edge_unit(u, OUT, ew_w, het, at1, at2, EB);
    else sf_unit<false>(spks, red, u-912, G, H1, HS, Sp, qmask, G, Gsum,
                        nullptr, nullptr, nullptr, nullptr);
  }
  grid_sync(cnt,nb,++tgt,false);

  // P7: hgGEMM2(164) + H1_k2(164) + HS_k2(164) + Sp_k2(16)
  for (unsigned u=bid; u<508; u+=nb){
    if (u<164)
      gemm_unit<1,true>(&sm, (u%41)*64, (u/41)*128, NNODE,
          nullptr, EB, he_w, nullptr,nullptr,nullptr,nullptr,nullptr,
          WT+(size_t)3*MATSZ, hcb+1024, OUT, 512, 0);
    else if (u<328){ unsigned v=u-164;
      gemm_unit<2,false>(&sm, (v%41)*64, (v/41)*128, NNODE,
          G,nullptr,nullptr,nullptr,nullptr,nullptr,nullptr,nullptr,
          WT+(size_t)10*MATSZ, nullptr, H1, 512, 0); }
    else if (u<492){ unsigned v=u-328;
      gemm_unit<2,false>(&sm, (v%41)*64, (v/41)*128, NNODE,
          G,nullptr,nullptr,nullptr,nullptr,nullptr,nullptr,nullptr,
          WT+(size_t)14*MATSZ, m3b+1024, HS, 512, 0); }
    else { unsigned v=u-492; int wh=v&1, ct=(v>>1)&3, rt=v>>3;
      gemm_unit<2,false>(&sm, rt*64, ct*128, 96,
          Gsum,nullptr,nullptr,nullptr,nullptr,nullptr,nullptr,nullptr,
          WT+(size_t)(4+wh*4+2)*MATSZ, nullptr, Sp, 1024, wh*512); }
  }
  grid_sync(cnt,nb,++tgt,false);

  // P8: sf_k2(96)
  for (unsigned u=bid; u<96; u+=nb)
    sf_unit<false>(spks, red, u, G, H1, HS, Sp, qmask, G, Gsum,
                   nullptr, nullptr, nullptr, nullptr);
  grid_sync(cnt,nb,++tgt,false);

  // P9: H1_k3(164) + HS_k3(164) + Sp_k3(16)
  for (unsigned u=bid; u<344; u+=nb){
    if (u<164)
      gemm_unit<2,false>(&sm, (u%41)*64, (u/41)*128, NNODE,
          G,nullptr,nullptr,nullptr,nullptr,nullptr,nullptr,nullptr,
          WT+(size_t)11*MATSZ, nullptr, H1, 512, 0);
    else if (u<328){ unsigned v=u-164;
      gemm_unit<2,false>(&sm, (v%41)*64, (v/41)*128, NNODE,
          G,nullptr,nullptr,nullptr,nullptr,nullptr,nullptr,nullptr,
          WT+(size_t)15*MATSZ, m3b+1536, HS, 512, 0); }
    else { unsigned v=u-328; int wh=v&1, ct=(v>>1)&3, rt=v>>3;
      gemm_unit<2,false>(&sm, rt*64, ct*128, 96,
          Gsum,nullptr,nullptr,nullptr,nullptr,nullptr,nullptr,nullptr,
          WT+(size_t)(4+wh*4+3)*MATSZ, nullptr, Sp, 1024, wh*512); }
  }
  grid_sync(cnt,nb,++tgt,false);

  // P10: sf_k3 LAST (96) — writes dout + denoise scalar
  for (unsigned u=bid; u<96; u+=nb)
    sf_unit<true>(spks, red, u, G, H1, HS, Sp, qmask, G, Gsum,
                  OUT, dout, acc, done);
}

// ---------------------------------------------------------------------------
extern "C" void kernel_launch(void* const* d_in, const int* in_sizes, int n_in,
                              void* d_out, int out_size, void* d_ws, size_t ws_size,
                              hipStream_t stream)
{
  const float* A_in   = (const float*)d_in[0];
  const float* V_in   = (const float*)d_in[1];
  const float* L_in   = (const float*)d_in[2];
  const float* qmask  = (const float*)d_in[3];
  const float* spk    = (const float*)d_in[4];
  const float* fc1_W  = (const float*)d_in[5];
  const float* fc1_b  = (const float*)d_in[6];
  const float* he_w   = (const float*)d_in[7];
  const float* ew_w   = (const float*)d_in[8];
  const float* attr1  = (const float*)d_in[9];
  const float* attr2  = (const float*)d_in[10];
  const float* hc_W   = (const float*)d_in[11];
  const float* hc_b   = (const float*)d_in[12];
  const float* m3_W0  = (const float*)d_in[13];
  const float* m3_W1  = (const float*)d_in[14];
  const float* m3_Ws  = (const float*)d_in[15];
  const float* m3_b   = (const float*)d_in[16];
  const int*   het    = (const int*)d_in[18];
  float* dout = (float*)d_out;

  char* ws = (char*)d_ws;
  unsigned int* ctrl = (unsigned int*)ws;             // 256 B control block
  ushort_t* WT = (ushort_t*)(ws + 256);               // 8 MB
  float* X1   = (float*)(ws + 256 + (size_t)16*MATSZ*2);
  float* OUT  = X1  + (size_t)NNODE*512;
  float* H1   = OUT + (size_t)NNODE*512;
  float* HS   = H1  + (size_t)NNODE*512;
  float* G    = HS  + (size_t)NNODE*512;
  float* EB   = G   + (size_t)NNODE*512;
  float* Gsum = EB  + (size_t)NEDGE*512;
  float* Sp   = Gsum + 96*512;

  (void)hipMemsetAsync(ctrl, 0, 256, stream);
  mega_kernel<<<NBLOCKS, 256, 0, stream>>>(
      A_in, V_in, L_in, qmask, spk, fc1_W, fc1_b, he_w, ew_w, attr1, attr2,
      hc_W, hc_b, m3_W0, m3_W1, m3_Ws, m3_b, het,
      WT, X1, OUT, H1, HS, G, EB, Gsum, Sp, ctrl, dout);

  (void)in_sizes; (void)n_in; (void)out_size; (void)ws_size;
}

// Round 8
// 575.635 us; speedup vs baseline: 1.1956x; 1.1956x over previous
//
#include <hip/hip_runtime.h>

typedef unsigned short ushort_t;
typedef __attribute__((ext_vector_type(4))) float f32x4;
typedef __attribute__((ext_vector_type(8))) short s16x8;
typedef __attribute__((ext_vector_type(8))) unsigned short u16x8;

#define NNODE 2592
#define NEDGE 912
#define MATSZ (512*512)
#define NBLOCKS 1024   // 4 blocks/CU: LDS 27K*4=108K<160K, VGPR<=128 via LB(256,4)
#define AS __HIP_MEMORY_SCOPE_AGENT

__device__ __forceinline__ ushort_t f2b(float f){
  union {unsigned int i; float f;} x; x.f = f;
  unsigned int r = (x.i + 0x7fffu + ((x.i>>16)&1u))>>16;
  return (ushort_t)r;
}
__device__ __forceinline__ void async_copy16(const ushort_t* g, ushort_t* l){
  __builtin_amdgcn_global_load_lds((const __attribute__((address_space(1))) void*)g,
                                   (__attribute__((address_space(3))) void*)l, 16, 0, 0);
}

// Coherent (L2-bypassing) access for inter-phase buffers. 16B loads via asm
// (sc0 sc1 = device-coherent); issue batched, waited once via pinned waitcnt.
__device__ __forceinline__ void ld4sc(f32x4& r, const float* p){
  asm volatile("global_load_dwordx4 %0, %1, off sc0 sc1" : "=v"(r) : "v"(p) : "memory");
}
__device__ __forceinline__ float cload(const float* p){
  return __hip_atomic_load(p, __ATOMIC_RELAXED, AS);
}
__device__ __forceinline__ void cstore(float* p, float v){
  __hip_atomic_store(p, v, __ATOMIC_RELAXED, AS);
}
__device__ __forceinline__ float2 cload2(const float* p){
  union{unsigned long long u; float2 f;} x;
  x.u = __hip_atomic_load((const unsigned long long*)p, __ATOMIC_RELAXED, AS);
  return x.f;
}
__device__ __forceinline__ void cstore2(float* p, float2 v){
  union{unsigned long long u; float2 f;} x; x.f = v;
  __hip_atomic_store((unsigned long long*)p, x.u, __ATOMIC_RELAXED, AS);
}

union SMem {
  struct { ushort_t As[64][72]; ushort_t Bs[128*64]; } g;  // 9216+16384 B
  float tile[64][65];                                      // 16640 B
};

// Hierarchical grid barrier: 16 group counters (64 blocks each, own cache
// lines) -> 1 global line touched by 16 leaders -> per-group done flags.
// Cuts same-line atomic contention ~64x vs single-counter (the R6/R7 cost).
// Monotonic counts, no reset race. fence=true only for WT publication.
__device__ __forceinline__ void grid_sync(unsigned int* ctrl,
                                          unsigned int target, bool fence){
  __syncthreads();
  if (threadIdx.x==0){
    if (fence) __builtin_amdgcn_fence(__ATOMIC_RELEASE, "agent");
    unsigned int g = blockIdx.x & 15u;
    unsigned int* gc = ctrl + g*32u;
    unsigned int* gd = ctrl + (16u+g)*32u;
    unsigned int* gl = ctrl + 32u*32u;
    unsigned int prev = __hip_atomic_fetch_add(gc, 1u, __ATOMIC_RELEASE, AS);
    if (prev == 64u*target - 1u){
      __hip_atomic_fetch_add(gl, 1u, __ATOMIC_RELEASE, AS);
      while (__hip_atomic_load(gl, __ATOMIC_RELAXED, AS) < 16u*target)
        __builtin_amdgcn_s_sleep(8);
      __hip_atomic_store(gd, target, __ATOMIC_RELAXED, AS);
    } else {
      while (__hip_atomic_load(gd, __ATOMIC_RELAXED, AS) < target)
        __builtin_amdgcn_s_sleep(8);
    }
    if (fence) __builtin_amdgcn_fence(__ATOMIC_ACQUIRE, "agent");
  }
  __syncthreads();
}

// ---- transpose+convert one 64x64 tile of one weight matrix ----
__device__ void transpose_unit(SMem* sm, unsigned u,
    const float* __restrict__ fc1, const float* __restrict__ hc,
    const float* __restrict__ m0, const float* __restrict__ m1,
    const float* __restrict__ ms, ushort_t* __restrict__ WT)
{
  unsigned w = u>>6, t = u&63;
  const float* src = (w==0) ? fc1
                   : (w<4)  ? hc + (size_t)(w-1)*MATSZ
                   : (w<8)  ? m0 + (size_t)(w-4)*MATSZ
                   : (w<12) ? m1 + (size_t)(w-8)*MATSZ
                            : ms + (size_t)(w-12)*MATSZ;
  ushort_t* dst = WT + (size_t)w*MATSZ;
  int r0 = (int)(t>>3)*64, c0 = (int)(t&7)*64;
  __syncthreads();
  #pragma unroll
  for (int j=0;j<16;j++){
    int idx = j*256 + threadIdx.x;
    int r = idx>>6, c = idx&63;
    sm->tile[r][c] = src[(size_t)(r0+r)*512 + c0 + c];
  }
  __syncthreads();
  #pragma unroll
  for (int j=0;j<16;j++){
    int idx = j*256 + threadIdx.x;
    int r = idx>>6, c = idx&63;
    dst[(size_t)(c0+r)*512 + r0 + c] = f2b(sm->tile[c][r]);
  }
}

// ---- one 64x128 GEMM tile (single-buffer K-loop, coherent 16B A loads) ----
// AMODE 0: A = feats (a/v/l + spk_emb);  1: hyperedge combine;  2: fp32 Asrc
template<int AMODE, bool RELU>
__device__ void gemm_unit(SMem* sm, int row0, int col0, int M,
    const float* __restrict__ Asrc, const float* __restrict__ Ebuf,
    const float* __restrict__ he_w,
    const float* __restrict__ inA, const float* __restrict__ inV,
    const float* __restrict__ inL, const float* __restrict__ qmask,
    const float* __restrict__ spk_emb,
    const ushort_t* __restrict__ Wsel, const float* __restrict__ bsel,
    float* __restrict__ Cout, int cst, int cbase)
{
  const int tid = threadIdx.x;
  const int wave = tid>>6, lane = tid&63;
  const int ml = lane&15, quad = lane>>4;
  const int wr = wave>>1, wc = wave&1;
  const int ar = tid>>3, ac8 = (tid&7)*8;

  const float *sr0=nullptr,*sr1=nullptr,*sp0=nullptr,*sp1=nullptr;
  const float *e10=nullptr,*e20=nullptr,*e11=nullptr,*e21=nullptr;
  float c10=0.f,c20=0.f,c11=0.f,c21=0.f;
  const float *g0=nullptr,*g1=nullptr;
  {
    int n0 = row0+ar;     if (n0 > M-1) n0 = M-1;
    int n1 = row0+ar+32;  if (n1 > M-1) n1 = M-1;
    if (AMODE==0){
      int d=n0/162, rm=n0-d*162, m=rm/54, i=rm-m*54, t=d*54+i;
      sr0 = ((m==0)? inL : (m==1)? inA : inV) + (size_t)t*512;
      if (m==0) sp0 = spk_emb + ((qmask[(i*16+d)*2+1]>qmask[(i*16+d)*2])?512:0);
      d=n1/162; rm=n1-d*162; m=rm/54; i=rm-m*54; t=d*54+i;
      sr1 = ((m==0)? inL : (m==1)? inA : inV) + (size_t)t*512;
      if (m==0) sp1 = spk_emb + ((qmask[(i*16+d)*2+1]>qmask[(i*16+d)*2])?512:0);
    } else if (AMODE==1){
      int d=n0/162, rm=n0-d*162, m=rm/54, i=rm-m*54;
      int em=d*57+m, eu=d*57+3+i;
      float w1=he_w[em], w2=he_w[eu], inv=1.0f/(w1+w2+1e-8f);
      c10=w1*inv; c20=w2*inv; e10=Ebuf+(size_t)em*512; e20=Ebuf+(size_t)eu*512;
      d=n1/162; rm=n1-d*162; m=rm/54; i=rm-m*54;
      em=d*57+m; eu=d*57+3+i;
      w1=he_w[em]; w2=he_w[eu]; inv=1.0f/(w1+w2+1e-8f);
      c11=w1*inv; c21=w2*inv; e11=Ebuf+(size_t)em*512; e21=Ebuf+(size_t)eu*512;
    } else {
      g0 = Asrc + (size_t)n0*512;
      g1 = Asrc + (size_t)n1*512;
    }
  }

  f32x4 acc[2][4];
  #pragma unroll
  for (int mi=0;mi<2;mi++)
    #pragma unroll
    for (int j=0;j<4;j++) acc[mi][j] = (f32x4){0.f,0.f,0.f,0.f};

  const int lr = lane>>3;
  const int lchunk = lane&7;
  const int bswz = (lchunk ^ lr)*8;

  for (int kt=0; kt<8; kt++){
    const int kk = kt*64;
    u16x8 av0, av1;
    if (AMODE==0){
      f32x4 xa=*(const f32x4*)(sr0+kk+ac8), xb=*(const f32x4*)(sr0+kk+ac8+4);
      if (sp0){
        f32x4 sa=*(const f32x4*)(sp0+kk+ac8), sb=*(const f32x4*)(sp0+kk+ac8+4);
        #pragma unroll
        for(int j=0;j<4;j++){ xa[j]+=sa[j]; xb[j]+=sb[j]; }
      }
      f32x4 ya=*(const f32x4*)(sr1+kk+ac8), yb=*(const f32x4*)(sr1+kk+ac8+4);
      if (sp1){
        f32x4 sa=*(const f32x4*)(sp1+kk+ac8), sb=*(const f32x4*)(sp1+kk+ac8+4);
        #pragma unroll
        for(int j=0;j<4;j++){ ya[j]+=sa[j]; yb[j]+=sb[j]; }
      }
      #pragma unroll
      for(int j=0;j<4;j++){
        av0[j]=f2b(xa[j]); av0[4+j]=f2b(xb[j]);
        av1[j]=f2b(ya[j]); av1[4+j]=f2b(yb[j]);
      }
    } else if (AMODE==1){
      f32x4 p0,p1,q0,q1,p2,p3,q2,q3;
      ld4sc(p0, e10+kk+ac8); ld4sc(p1, e10+kk+ac8+4);
      ld4sc(q0, e20+kk+ac8); ld4sc(q1, e20+kk+ac8+4);
      ld4sc(p2, e11+kk+ac8); ld4sc(p3, e11+kk+ac8+4);
      ld4sc(q2, e21+kk+ac8); ld4sc(q3, e21+kk+ac8+4);
      asm volatile("s_waitcnt vmcnt(0)"
        : "+v"(p0),"+v"(p1),"+v"(q0),"+v"(q1),
          "+v"(p2),"+v"(p3),"+v"(q2),"+v"(q3));
      #pragma unroll
      for(int j=0;j<4;j++){
        av0[j]   = f2b(c10*p0[j] + c20*q0[j]);
        av0[4+j] = f2b(c10*p1[j] + c20*q1[j]);
        av1[j]   = f2b(c11*p2[j] + c21*q2[j]);
        av1[4+j] = f2b(c11*p3[j] + c21*q3[j]);
      }
    } else {
      f32x4 p0,p1,p2,p3;
      ld4sc(p0, g0+kk+ac8); ld4sc(p1, g0+kk+ac8+4);
      ld4sc(p2, g1+kk+ac8); ld4sc(p3, g1+kk+ac8+4);
      asm volatile("s_waitcnt vmcnt(0)"
        : "+v"(p0),"+v"(p1),"+v"(p2),"+v"(p3));
      #pragma unroll
      for(int j=0;j<4;j++){
        av0[j]=f2b(p0[j]); av0[4+j]=f2b(p1[j]);
        av1[j]=f2b(p2[j]); av1[4+j]=f2b(p3[j]);
      }
    }
    __syncthreads();   // previous iter's MFMA LDS reads complete
    *(u16x8*)&sm->g.As[ar][ac8]    = av0;
    *(u16x8*)&sm->g.As[ar+32][ac8] = av1;
    #pragma unroll
    for (int rep=0; rep<4; rep++){
      int bn0 = wave*32 + rep*8;
      const ushort_t* s = Wsel + (size_t)(col0 + bn0 + lr)*512 + kk + bswz;
      async_copy16(s, &sm->g.Bs[bn0*64]);
    }
    __syncthreads();   // As visible + B DMA drained (vmcnt0 before barrier)
    #pragma unroll
    for (int kh=0; kh<2; kh++){
      s16x8 a0 = *(const s16x8*)&sm->g.As[wr*32 + ml][kh*32 + quad*8];
      s16x8 a1 = *(const s16x8*)&sm->g.As[wr*32 + 16 + ml][kh*32 + quad*8];
      s16x8 b[4];
      #pragma unroll
      for (int j=0;j<4;j++){
        int bn = wc*64 + j*16 + ml;
        b[j] = *(const s16x8*)&sm->g.Bs[bn*64 + (((kh*4+quad) ^ (bn&7))<<3)];
      }
      #pragma unroll
      for (int j=0;j<4;j++){
        acc[0][j] = __builtin_amdgcn_mfma_f32_16x16x32_bf16(a0,b[j],acc[0][j],0,0,0);
        acc[1][j] = __builtin_amdgcn_mfma_f32_16x16x32_bf16(a1,b[j],acc[1][j],0,0,0);
      }
    }
  }

  #pragma unroll
  for (int j=0;j<4;j++){
    int wcol = col0 + wc*64 + j*16 + ml;
    float bv = bsel ? bsel[wcol] : 0.f;
    int c = cbase + wcol;
    #pragma unroll
    for (int mi=0;mi<2;mi++){
      int rb = row0 + wr*32 + mi*16 + quad*4;
      f32x4 a = acc[mi][j];
      #pragma unroll
      for (int r=0;r<4;r++){
        int rr = rb + r;
        if (rr < M){
          float v = a[r] + bv;
          if (RELU) v = fmaxf(v, 0.f);
          cstore(Cout + (size_t)rr*cst + c, v);
        }
      }
    }
  }
  __syncthreads();
}

// ---- one hyperedge: e = (sum w*x)/(sum w+eps) + attr ----
__device__ void edge_unit(int e, const float* __restrict__ X,
    const float* __restrict__ ew, const int* __restrict__ het,
    const float* __restrict__ at1, const float* __restrict__ at2,
    float* __restrict__ E)
{
  int d = e/57, r = e - d*57;
  int col = threadIdx.x*2;
  float sx=0.f, sy=0.f, de=0.f;
  if (r < 3){
    int nnz0 = d*324 + r*54;
    const float* row = X + ((size_t)(d*162 + r*54))*512 + col;
    #pragma unroll 9
    for (int i=0;i<54;i++){
      float w = ew[nnz0+i];
      float2 x = cload2(row);
      sx += w*x.x; sy += w*x.y; de += w;
      row += 512;
    }
  } else {
    int i = r-3;
    int nnz0 = d*324 + 162 + i*3;
    #pragma unroll
    for (int m=0;m<3;m++){
      float w = ew[nnz0+m];
      float2 x = cload2(X + ((size_t)(d*162 + m*54 + i))*512 + col);
      sx += w*x.x; sy += w*x.y; de += w;
    }
  }
  float invde = 1.0f/(de + 1e-8f);
  const float* at = het[e] ? at1 : at2;
  float2 o;
  o.x = sx*invde + at[col];
  o.y = sy*invde + at[col+1];
  cstore2(E + (size_t)e*512 + col, o);
}

// ---- per-(group,speaker) column sums of X ----
__device__ void gsum_unit(unsigned char* spks, int u, const float* __restrict__ X,
    const float* __restrict__ qmask, float* __restrict__ Gsum)
{
  int g = u>>1, d = g/3;
  int col = (u&1)*256 + threadIdx.x;
  __syncthreads();
  if (threadIdx.x < 54)
    spks[threadIdx.x] = qmask[(threadIdx.x*16+d)*2+1] > qmask[(threadIdx.x*16+d)*2];
  __syncthreads();
  size_t base = (size_t)g*54*512 + col;
  float s0=0.f, s1=0.f;
  #pragma unroll 9
  for (int i=0;i<54;i++){
    float x = cload(X + base + (size_t)i*512);
    if (spks[i]) s1 += x; else s0 += x;
  }
  cstore(Gsum + (size_t)(g*2)*512 + col, s0);
  cstore(Gsum + (size_t)(g*2+1)*512 + col, s1);
}

// ---- fused RGCN combine + next-layer Gsum (+final output & denoise) ----
template<bool LAST>
__device__ void sf_unit(unsigned char* spks, float* red, int u,
    const float* __restrict__ Gin, const float* __restrict__ H1,
    const float* __restrict__ HS, const float* __restrict__ Sp,
    const float* __restrict__ qmask, float* __restrict__ Gout,
    float* __restrict__ Gsum, const float* __restrict__ OUThg,
    float* __restrict__ dout, float* __restrict__ acc,
    unsigned int* __restrict__ done)
{
  int g = u>>1, d = g/3;
  int col = (u&1)*256 + threadIdx.x;
  __syncthreads();
  if (threadIdx.x < 54)
    spks[threadIdx.x] = qmask[(threadIdx.x*16+d)*2+1] > qmask[(threadIdx.x*16+d)*2];
  __syncthreads();
  float S1_0 = cload(Sp + (size_t)(g*2)*1024 + 512 + col);
  float S1_1 = cload(Sp + (size_t)(g*2+1)*1024 + 512 + col);
  float S0_0 = cload(Sp + (size_t)(g*2+1)*1024 + col);
  float S0_1 = cload(Sp + (size_t)(g*2)*1024 + col);
  const float inv = 1.0f/(53.0f + 1e-8f);
  size_t base = (size_t)g*54*512 + col;
  float gs0=0.f, gs1=0.f, sumsq=0.f;
  #pragma unroll 6
  for (int i=0;i<54;i++){
    size_t off = base + (size_t)i*512;
    int sp = spks[i];
    float S1 = sp ? S1_1 : S1_0;
    float S0 = sp ? S0_1 : S0_0;
    float h1 = cload(H1+off), hs = cload(HS+off), gi = cload(Gin+off);
    float f = fmaxf((S1 - h1 + S0)*inv + hs, 0.f);
    float gn = gi + f;
    cstore(Gout+off, gn);
    if (sp) gs1 += gn; else gs0 += gn;
    if (LAST){
      sumsq += f*f;
      dout[off] = cload(OUThg+off) + gn;
    }
  }
  cstore(Gsum + (size_t)(g*2)*512 + col, gs0);
  cstore(Gsum + (size_t)(g*2+1)*512 + col, gs1);
  if (LAST){
    red[threadIdx.x] = sumsq;
    __syncthreads();
    #pragma unroll
    for (int s=128; s>0; s>>=1){
      if (threadIdx.x < s) red[threadIdx.x] += red[threadIdx.x+s];
      __syncthreads();
    }
    if (threadIdx.x == 0){
      atomicAdd(acc, red[0]);
      __threadfence();
      unsigned int old = atomicAdd(done, 1u);
      if (old == 95u){
        float tot = atomicAdd(acc, 0.0f);
        dout[(size_t)NNODE*512] = tot * (1.0f/1327104.0f);
      }
    }
  }
}

// ---------------------------------------------------------------------------
__global__ __launch_bounds__(256,4) void mega_kernel(
    const float* __restrict__ A_in, const float* __restrict__ V_in,
    const float* __restrict__ L_in, const float* __restrict__ qmask,
    const float* __restrict__ spk_emb,
    const float* __restrict__ fc1W, const float* __restrict__ fc1b,
    const float* __restrict__ he_w, const float* __restrict__ ew_w,
    const float* __restrict__ at1, const float* __restrict__ at2,
    const float* __restrict__ hcW, const float* __restrict__ hcb,
    const float* __restrict__ m0W, const float* __restrict__ m1W,
    const float* __restrict__ msW, const float* __restrict__ m3b,
    const int* __restrict__ het,
    ushort_t* __restrict__ WT, float* __restrict__ X1, float* __restrict__ OUT,
    float* __restrict__ H1, float* __restrict__ HS, float* __restrict__ G,
    float* __restrict__ EB, float* __restrict__ Gsum, float* __restrict__ Sp,
    unsigned int* __restrict__ ctrl, float* __restrict__ dout)
{
  __shared__ SMem sm;
  __shared__ unsigned char spks[64];
  __shared__ float red[256];
  unsigned int* done = ctrl + 33*32;
  float* acc = (float*)(ctrl + 34*32);
  const unsigned int bid = blockIdx.x, nb = gridDim.x;
  unsigned int tgt = 0;

  // P0: weight transpose (1024 units)
  for (unsigned u=bid; u<1024; u+=nb)
    transpose_unit(&sm, u, fc1W, hcW, m0W, m1W, msW, WT);
  grid_sync(ctrl,++tgt,true);   // ONLY fenced barrier: publishes WT

  // P1: X1 = feats @ fc1 + b (164 units)
  for (unsigned u=bid; u<164; u+=nb)
    gemm_unit<0,false>(&sm, (u%41)*64, (u/41)*128, NNODE,
        nullptr,nullptr,nullptr, A_in,V_in,L_in,qmask,spk_emb,
        WT, fc1b, X1, 512, 0);
  grid_sync(ctrl,++tgt,false);

  // P2: edge0(912) + gsum(96) + H1_k0(164) + HS_k0(164)
  for (unsigned u=bid; u<1336; u+=nb){
    if (u<912) edge_unit(u, X1, ew_w, het, at1, at2, EB);
    else if (u<1008) gsum_unit(spks, u-912, X1, qmask, Gsum);
    else if (u<1172){ unsigned v=u-1008;
      gemm_unit<2,false>(&sm, (v%41)*64, (v/41)*128, NNODE,
          X1,nullptr,nullptr,nullptr,nullptr,nullptr,nullptr,nullptr,
          WT+(size_t)8*MATSZ, nullptr, H1, 512, 0); }
    else { unsigned v=u-1172;
      gemm_unit<2,false>(&sm, (v%41)*64, (v/41)*128, NNODE,
          X1,nullptr,nullptr,nullptr,nullptr,nullptr,nullptr,nullptr,
          WT+(size_t)12*MATSZ, m3b, HS, 512, 0); }
  }
  grid_sync(ctrl,++tgt,false);

  // P3: hgGEMM0(164) + Sp_k0(16)
  for (unsigned u=bid; u<180; u+=nb){
    if (u<164)
      gemm_unit<1,true>(&sm, (u%41)*64, (u/41)*128, NNODE,
          nullptr, EB, he_w, nullptr,nullptr,nullptr,nullptr,nullptr,
          WT+(size_t)1*MATSZ, hcb, OUT, 512, 0);
    else { unsigned v=u-164; int wh=v&1, ct=(v>>1)&3, rt=v>>3;
      gemm_unit<2,false>(&sm, rt*64, ct*128, 96,
          Gsum,nullptr,nullptr,nullptr,nullptr,nullptr,nullptr,nullptr,
          WT+(size_t)(4+wh*4+0)*MATSZ, nullptr, Sp, 1024, wh*512); }
  }
  grid_sync(ctrl,++tgt,false);

  // P4: edge1(912, X=OUT) + sf_k0(96)
  for (unsigned u=bid; u<1008; u+=nb){
    if (u<912) edge_unit(u, OUT, ew_w, het, at1, at2, EB);
    else sf_unit<false>(spks, red, u-912, X1, H1, HS, Sp, qmask, G, Gsum,
                        nullptr, nullptr, nullptr, nullptr);
  }
  grid_sync(ctrl,++tgt,false);

  // P5: hgGEMM1(164) + H1_k1(164) + HS_k1(164) + Sp_k1(16)
  for (unsigned u=bid; u<508; u+=nb){
    if (u<164)
      gemm_unit<1,true>(&sm, (u%41)*64, (u/41)*128, NNODE,
          nullptr, EB, he_w, nullptr,nullptr,nullptr,nullptr,nullptr,
          WT+(size_t)2*MATSZ, hcb+512, OUT, 512, 0);
    else if (u<328){ unsigned v=u-164;
      gemm_unit<2,false>(&sm, (v%41)*64, (v/41)*128, NNODE,
          G,nullptr,nullptr,nullptr,nullptr,nullptr,nullptr,nullptr,
          WT+(size_t)9*MATSZ, nullptr, H1, 512, 0); }
    else if (u<492){ unsigned v=u-328;
      gemm_unit<2,false>(&sm, (v%41)*64, (v/41)*128, NNODE,
          G,nullptr,nullptr,nullptr,nullptr,nullptr,nullptr,nullptr,
          WT+(size_t)13*MATSZ, m3b+512, HS, 512, 0); }
    else { unsigned v=u-492; int wh=v&1, ct=(v>>1)&3, rt=v>>3;
      gemm_unit<2,false>(&sm, rt*64, ct*128, 96,
          Gsum,nullptr,nullptr,nullptr,nullptr,nullptr,nullptr,nullptr,
          WT+(size_t)(4+wh*4+1)*MATSZ, nullptr, Sp, 1024, wh*512); }
  }
  grid_sync(ctrl,++tgt,false);

  // P6: edge2(912, X=OUT) + sf_k1(96)
  for (unsigned u=bid; u<1008; u+=nb){
    if (u<912) edge_unit(u, OUT, ew_w, het, at1, at2, EB);
    else sf_unit<false>(spks, red, u-912, G, H1, HS, Sp, qmask, G, Gsum,
                        nullptr, nullptr, nullptr, nullptr);
  }
  grid_sync(ctrl,++tgt,false);

  // P7: hgGEMM2(164) + H1_k2(164) + HS_k2(164) + Sp_k2(16)
  for (unsigned u=bid; u<508; u+=nb){
    if (u<164)
      gemm_unit<1,true>(&sm, (u%41)*64, (u/41)*128, NNODE,
          nullptr, EB, he_w, nullptr,nullptr,nullptr,nullptr,nullptr,
          WT+(size_t)3*MATSZ, hcb+1024, OUT, 512, 0);
    else if (u<328){ unsigned v=u-164;
      gemm_unit<2,false>(&sm, (v%41)*64, (v/41)*128, NNODE,
          G,nullptr,nullptr,nullptr,nullptr,nullptr,nullptr,nullptr,
          WT+(size_t)10*MATSZ, nullptr, H1, 512, 0); }
    else if (u<492){ unsigned v=u-328;
      gemm_unit<2,false>(&sm, (v%41)*64, (v/41)*128, NNODE,
          G,nullptr,nullptr,nullptr,nullptr,nullptr,nullptr,nullptr,
          WT+(size_t)14*MATSZ, m3b+1024, HS, 512, 0); }
    else { unsigned v=u-492; int wh=v&1, ct=(v>>1)&3, rt=v>>3;
      gemm_unit<2,false>(&sm, rt*64, ct*128, 96,
          Gsum,nullptr,nullptr,nullptr,nullptr,nullptr,nullptr,nullptr,
          WT+(size_t)(4+wh*4+2)*MATSZ, nullptr, Sp, 1024, wh*512); }
  }
  grid_sync(ctrl,++tgt,false);

  // P8: sf_k2(96)
  for (unsigned u=bid; u<96; u+=nb)
    sf_unit<false>(spks, red, u, G, H1, HS, Sp, qmask, G, Gsum,
                   nullptr, nullptr, nullptr, nullptr);
  grid_sync(ctrl,++tgt,false);

  // P9: H1_k3(164) + HS_k3(164) + Sp_k3(16)
  for (unsigned u=bid; u<344; u+=nb){
    if (u<164)
      gemm_unit<2,false>(&sm, (u%41)*64, (u/41)*128, NNODE,
          G,nullptr,nullptr,nullptr,nullptr,nullptr,nullptr,nullptr,
          WT+(size_t)11*MATSZ, nullptr, H1, 512, 0);
    else if (u<328){ unsigned v=u-164;
      gemm_unit<2,false>(&sm, (v%41)*64, (v/41)*128, NNODE,
          G,nullptr,nullptr,nullptr,nullptr,nullptr,nullptr,nullptr,
          WT+(size_t)15*MATSZ, m3b+1536, HS, 512, 0); }
    else { unsigned v=u-328; int wh=v&1, ct=(v>>1)&3, rt=v>>3;
      gemm_unit<2,false>(&sm, rt*64, ct*128, 96,
          Gsum,nullptr,nullptr,nullptr,nullptr,nullptr,nullptr,nullptr,
          WT+(size_t)(4+wh*4+3)*MATSZ, nullptr, Sp, 1024, wh*512); }
  }
  grid_sync(ctrl,++tgt,false);

  // P10: sf_k3 LAST (96) — writes dout + denoise scalar
  for (unsigned u=bid; u<96; u+=nb)
    sf_unit<true>(spks, red, u, G, H1, HS, Sp, qmask, G, Gsum,
                  OUT, dout, acc, done);
}

// ---------------------------------------------------------------------------
extern "C" void kernel_launch(void* const* d_in, const int* in_sizes, int n_in,
                              void* d_out, int out_size, void* d_ws, size_t ws_size,
                              hipStream_t stream)
{
  const float* A_in   = (const float*)d_in[0];
  const float* V_in   = (const float*)d_in[1];
  const float* L_in   = (const float*)d_in[2];
  const float* qmask  = (const float*)d_in[3];
  const float* spk    = (const float*)d_in[4];
  const float* fc1_W  = (const float*)d_in[5];
  const float* fc1_b  = (const float*)d_in[6];
  const float* he_w   = (const float*)d_in[7];
  const float* ew_w   = (const float*)d_in[8];
  const float* attr1  = (const float*)d_in[9];
  const float* attr2  = (const float*)d_in[10];
  const float* hc_W   = (const float*)d_in[11];
  const float* hc_b   = (const float*)d_in[12];
  const float* m3_W0  = (const float*)d_in[13];
  const float* m3_W1  = (const float*)d_in[14];
  const float* m3_Ws  = (const float*)d_in[15];
  const float* m3_b   = (const float*)d_in[16];
  const int*   het    = (const int*)d_in[18];
  float* dout = (float*)d_out;

  char* ws = (char*)d_ws;
  unsigned int* ctrl = (unsigned int*)ws;             // 8 KB control block
  ushort_t* WT = (ushort_t*)(ws + 8192);              // 8 MB
  float* X1   = (float*)(ws + 8192 + (size_t)16*MATSZ*2);
  float* OUT  = X1  + (size_t)NNODE*512;
  float* H1   = OUT + (size_t)NNODE*512;
  float* HS   = H1  + (size_t)NNODE*512;
  float* G    = HS  + (size_t)NNODE*512;
  float* EB   = G   + (size_t)NNODE*512;
  float* Gsum = EB  + (size_t)NEDGE*512;
  float* Sp   = Gsum + 96*512;

  (void)hipMemsetAsync(ctrl, 0, 8192, stream);
  mega_kernel<<<NBLOCKS, 256, 0, stream>>>(
      A_in, V_in, L_in, qmask, spk, fc1_W, fc1_b, he_w, ew_w, attr1, attr2,
      hc_W, hc_b, m3_W0, m3_W1, m3_Ws, m3_b, het,
      WT, X1, OUT, H1, HS, G, EB, Gsum, Sp, ctrl, dout);

  (void)in_sizes; (void)n_in; (void)out_size; (void)ws_size;
}